// Round 17
// baseline (1743.363 us; speedup 1.0000x reference)
//
#include <hip/hip_runtime.h>
#include <stdint.h>
#include <math.h>

typedef unsigned long long u64;
typedef unsigned int u32;

#define CIN     1024
#define COUT    512
#define FH      50
#define FW      76
#define QP      80
#define HIDP    4096
#define FPITCH  4160            // 52*80
#define NPOS    3800
#define NA      34200
#define PRE_N   4000
#define POST_N  2000
#define MASKW   63
#define TBN     4032
#define KSLICES 8
#define CPS     128             // cins per slice; fold every 8 cins -> 72-ks fp32 segments (bit-identical)
#define QT      128             // q-tile (2 q per lane)
#define SPP     (CPS/2)         // cin-pair steps per slice = 64

#define P0 (3*CIN*FPITCH)       // fpad3 elements
#define P2 (512*48)             // wT elements
#define P3 65536                // init range
#define PREP_BLKS ((P0+P2+P3)/256)   // 50272
#define WT_BLKS   (144*8)            // 1152 transpose tiles

// ---------------- async global->LDS (16B granule: per-lane src, lds dest = base + lane*16)
__device__ __forceinline__ void async16(const float* g, float* l) {
  __builtin_amdgcn_global_load_lds(
      (__attribute__((address_space(1))) void*)(g),
      (__attribute__((address_space(3))) void*)(l), 16, 0, 0);
}

// ---------------- K0: fused prep — fpad3, conv-weight transpose, wT/bT, init
__global__ void k_prep(const float* __restrict__ feats, const float* __restrict__ w_conv,
                       const float* __restrict__ w_cls, const float* __restrict__ b_cls,
                       const float* __restrict__ w_reg, const float* __restrict__ b_reg,
                       float* __restrict__ fpad3, float* __restrict__ wt,
                       float* __restrict__ wT, float* __restrict__ bT,
                       u32* __restrict__ hist, u32* __restrict__ ctrl, u32* __restrict__ cnt,
                       double4* __restrict__ tb, float* __restrict__ ts) {
  __shared__ float t[64][65];
  if (blockIdx.x >= PREP_BLKS) {
    // proven R1 transpose tile: w[oc][k] -> wt[k][oc]
    int bt_ = blockIdx.x - PREP_BLKS;
    int kx = bt_ % 144, oy = bt_ / 144;
    int k0 = kx * 64, oc0 = oy * 64;
    int tx = threadIdx.x & 63, tg = threadIdx.x >> 6;
#pragma unroll
    for (int rr = 0; rr < 16; rr++) {
      int row = tg * 16 + rr;
      t[row][tx] = w_conv[(size_t)(oc0 + row) * 9216 + k0 + tx];
    }
    __syncthreads();
#pragma unroll
    for (int rr = 0; rr < 16; rr++) {
      int kr = tg * 16 + rr;
      wt[(size_t)(k0 + kr) * 512 + oc0 + tx] = t[tx][kr];
    }
    return;
  }
  int idx = blockIdx.x * 256 + threadIdx.x;
  if (idx < P0) {
    int tc = idx / (CIN * FPITCH);
    int rem = idx - tc * (CIN * FPITCH);
    int cin = rem / FPITCH;
    int j = rem - cin * FPITCH + tc;
    float v = 0.f;
    if (j < FPITCH) {
      int r = j / QP, u = j - r * QP;
      if (r >= 1 && r <= FH && u >= 1 && u <= FW)
        v = feats[cin * (FH * FW) + (r - 1) * FW + (u - 1)];
    }
    fpad3[idx] = v;
    return;
  }
  idx -= P0;
  if (idx < P2) {
    int c = idx / 48, o = idx - c * 48;
    float v = 0.f;
    if (o < 9) v = w_cls[(size_t)(9 + o) * 512 + c];
    else if (o < 45) v = w_reg[(size_t)(o - 9) * 512 + c];
    wT[idx] = v;
    return;
  }
  idx -= P2;
  if (idx < P3) {
    hist[idx] = 0;
    if (idx < 16) ctrl[idx] = 0;
    if (idx < 512) cnt[idx] = 0;
    if (idx < 48) bT[idx] = (idx < 9) ? b_cls[9 + idx] : (idx < 45 ? b_reg[idx - 9] : 0.f);
    if (idx >= PRE_N && idx < TBN) { tb[idx] = make_double4(0.0, 0.0, 0.0, 0.0); ts[idx] = -1.0e9f; }
  }
}

// ---------------- K2: conv3x3 split-K (R11-proven core); LAST z-slice block of each
//                  (q,oc) tile performs the 8-slice reduce+bias+relu (replaces k_reduce)
__global__ __launch_bounds__(256, 6) void k_conv(const float* __restrict__ fpad3,
                                                 const float* __restrict__ wt,
                                                 const float* __restrict__ bconv,
                                                 float* __restrict__ hidp,
                                                 float* __restrict__ hid,
                                                 u32* __restrict__ cnt) {
  __shared__ __align__(16) float Bl[2][2][10][QT];   // 20.5 KiB: [buf][ci][row(9+dup)][q]
  __shared__ bool lastb;
  const int tid = threadIdx.x;
  const int lane = tid & 63;
  const int wv = __builtin_amdgcn_readfirstlane(tid >> 6);
  const int q0 = blockIdx.x * QT;                    // 32 q-tiles of 128
  const int ws = (blockIdx.y << 2) + wv;             // oc-slice 0..63 (8 oc each)
  const int c0 = blockIdx.z * CPS;

  // wave wv stages rows 2wv (lanes 0-31), 2wv+1 (lanes 32-63); wave 0 also row 8 (dup 8,9)
  int rA = 2 * wv + (lane >> 5);
  int trA = rA / 3, tcA = rA - trA * 3;
  u32 voffA = (u32)tcA * (CIN * FPITCH) + (u32)trA * QP + q0 + (lane & 31) * 4;
  u32 voffB = 2u * (CIN * FPITCH) + 2u * QP + q0 + (lane & 31) * 4;   // row 8

  float acc32[8][2];
  double acc64[8][2];
#pragma unroll
  for (int i = 0; i < 8; i++) {
    acc32[i][0] = acc32[i][1] = 0.f;
    acc64[i][0] = acc64[i][1] = 0.0;
  }

#define STAGE(buf, sp)  do {                                                    \
    const float* _b0 = fpad3 + (size_t)(c0 + 2 * (sp)) * FPITCH;                \
    async16(_b0 + voffA, &Bl[buf][0][2 * wv][0]);                               \
    if (wv == 0) async16(_b0 + voffB, &Bl[buf][0][8][0]);                       \
    const float* _b1 = _b0 + FPITCH;                                            \
    async16(_b1 + voffA, &Bl[buf][1][2 * wv][0]);                               \
    if (wv == 0) async16(_b1 + voffB, &Bl[buf][1][8][0]);                       \
  } while (0)

  STAGE(0, 0);

#pragma unroll 1
  for (int sp = 0; sp < SPP; sp++) {
    __syncthreads();                                 // stage(sp) landed
    if (sp + 1 < SPP) STAGE((sp + 1) & 1, sp + 1);
    const int b0 = sp & 1;
#pragma unroll
    for (int ci = 0; ci < 2; ci++) {
      const int cin = c0 + 2 * sp + ci;
      const float* wp = wt + (((size_t)cin * 9) << 9) + (ws << 3);   // uniform -> s_load
#pragma unroll
      for (int ks = 0; ks < 9; ks++) {
        float2 b2 = *(const float2*)&Bl[b0][ci][ks][lane * 2];
        const float* w8 = wp + (ks << 9);
#pragma unroll
        for (int i = 0; i < 8; i++) {
          float w = w8[i];
          acc32[i][0] = fmaf(w, b2.x, acc32[i][0]);
          acc32[i][1] = fmaf(w, b2.y, acc32[i][1]);
        }
      }
    }
    if ((sp & 3) == 3) {                             // fold every 4 pairs = 8 cins (72 ks)
#pragma unroll
      for (int i = 0; i < 8; i++) {
        acc64[i][0] += (double)acc32[i][0]; acc32[i][0] = 0.f;
        acc64[i][1] += (double)acc32[i][1]; acc32[i][1] = 0.f;
      }
    }
  }
#undef STAGE

#pragma unroll
  for (int i = 0; i < 8; i++) {
    float2 o;
    o.x = (float)acc64[i][0];
    o.y = (float)acc64[i][1];
    *(float2*)&hidp[((size_t)(blockIdx.z * COUT + (ws << 3) + i) << 12) + q0 + lane * 2] = o;
  }

  // ---- last-slice finisher: reduce this tile's 8 partials (z-ascending, == old k_reduce)
  __threadfence();                                   // release our partials
  if (tid == 0)
    lastb = (atomicAdd(&cnt[blockIdx.y * 32 + blockIdx.x], 1u) == KSLICES - 1);
  __syncthreads();
  if (!lastb) return;
  __threadfence();                                   // acquire others' partials
  const int ocb2 = blockIdx.y << 5;
#pragma unroll 1
  for (int e = tid; e < 32 * QT; e += 256) {
    int oc = ocb2 + (e >> 7);
    size_t base = ((size_t)oc << 12) + q0 + (e & 127);
    double s = 0.0;
#pragma unroll
    for (int z = 0; z < KSLICES; z++)
      s += (double)hidp[base + ((size_t)z << 21)];
    s += (double)bconv[oc];
    hid[base] = s > 0.0 ? (float)s : 0.f;
  }
}

// ---------------- K3: 1x1 conv heads; grid (64,4), 3 outputs/thread, fp64 c-ascending
__global__ __launch_bounds__(256, 8) void k_head(const float* __restrict__ hid,
                                                 const float* __restrict__ wT,
                                                 const float* __restrict__ bT,
                                                 float* __restrict__ scoresb,
                                                 float* __restrict__ deltab) {
  int lane = threadIdx.x & 63;
  int wv = threadIdx.x >> 6;
  int q = blockIdx.x * 64 + lane;            // padded-q space
  int og = blockIdx.y * 12 + wv * 3;         // output group base (0..45)
  double acc0 = 0.0, acc1 = 0.0, acc2 = 0.0;
#pragma unroll 4
  for (int c = 0; c < 512; c++) {
    double hv = (double)hid[((size_t)c << 12) + q];
    const float* wr = wT + c * 48 + og;      // uniform per wave -> s_load
    acc0 += hv * (double)wr[0];
    acc1 += hv * (double)wr[1];
    acc2 += hv * (double)wr[2];
  }
  int y = q / QP, x = q - y * QP;
  if (x < FW && y < FH) {
    int pos = y * FW + x;
    double a[3] = {acc0, acc1, acc2};
#pragma unroll
    for (int j = 0; j < 3; j++) {
      int o = og + j;
      float r = (float)(a[j] + (double)bT[o]);
      if (o < 9)       scoresb[o * NPOS + pos] = r;
      else if (o < 45) deltab[(o - 9) * NPOS + pos] = r;
    }
  }
}

// ---------------- K4: proposals + keys + transposed histogram; LAST block runs the
//                  cutoff-bin scan (replaces k_scan)
__device__ __constant__ float AW[9] = {184.f, 368.f, 736.f, 128.f, 256.f, 512.f, 88.f, 176.f, 352.f};
__device__ __constant__ float AH[9] = {96.f, 192.f, 384.f, 128.f, 256.f, 512.f, 176.f, 352.f, 704.f};

__global__ void k_prop(const float* __restrict__ scoresb, const float* __restrict__ deltab,
                       double4* __restrict__ boxesd, u64* __restrict__ keys,
                       float* __restrict__ smask, u32* __restrict__ hist,
                       u32* __restrict__ ctrl, float* __restrict__ dout) {
  __shared__ u32 cs[256];
  __shared__ u32 sfx[256];
  __shared__ bool lastb;
  const int tid = threadIdx.x;
  int g = blockIdx.x * 256 + tid;
  if (g < 10000) dout[g] = 0.f;            // zero the harness-poisoned output
  if (g < NA) {
    int pos = g / 9, a = g - pos * 9;
    int y = pos / FW, x = pos - y * FW;
    double w = (double)AW[a], h = (double)AH[a];
    double cx = x * 16.0 + 8.0, cy = y * 16.0 + 8.0;
    double d0 = (double)deltab[(4 * a + 0) * NPOS + pos];
    double d1 = (double)deltab[(4 * a + 1) * NPOS + pos];
    double d2 = (double)deltab[(4 * a + 2) * NPOS + pos];
    double d3 = (double)deltab[(4 * a + 3) * NPOS + pos];
    double pcx = d0 * w + cx, pcy = d1 * h + cy;
    double pw = exp(d2) * w, ph = exp(d3) * h;
    double px1 = fmin(fmax(pcx - 0.5 * pw, 0.0), 1215.0);
    double py1 = fmin(fmax(pcy - 0.5 * ph, 0.0), 799.0);
    double px2 = fmin(fmax(pcx + 0.5 * pw, 0.0), 1215.0);
    double py2 = fmin(fmax(pcy + 0.5 * ph, 0.0), 799.0);
    bool valid = (px2 - px1 + 1.0 >= 16.0) && (py2 - py1 + 1.0 >= 16.0);
    float sc = scoresb[a * NPOS + pos];
    float ms = valid ? sc : -1.0e9f;
    boxesd[g] = make_double4(px1, py1, px2, py2);
    smask[g] = ms;
    u32 u = __float_as_uint(ms);
    u = (u >> 31) ? ~u : (u | 0x80000000u);          // monotone float->uint
    keys[g] = ((u64)u << 32) | (u32)(~(u32)g);       // score desc, index asc
    atomicAdd(&hist[(((u >> 16) & 0xFFu) << 8) | (u >> 24)], 1u);   // transposed bin
  }
  // ---- last-block finisher: histogram cutoff scan
  __threadfence();
  if (tid == 0) lastb = (atomicAdd(&ctrl[8], 1u) == 133u);
  __syncthreads();
  if (!lastb) return;
  __threadfence();
  u32 s = 0;
  for (int i = 0; i < 256; i++) s += hist[(i << 8) | tid];   // coalesced
  cs[tid] = s;
  __syncthreads();
  if (tid == 0) {
    u32 c = 0;
    for (int i = 255; i >= 0; i--) { sfx[i] = c; c += cs[i]; }
  }
  __syncthreads();
  u32 before = sfx[tid];
  u32 c = 0;
  for (int blo = 255; blo >= 0; blo--) {
    u32 hv = hist[(blo << 8) | tid];
    if (before + c < PRE_N && before + c + hv >= PRE_N) {
      ctrl[0] = (u32)(tid * 256 + blo);  // cutoff bin B (untransposed id)
      ctrl[1] = before + c;              // count strictly above B
    }
    c += hv;
  }
}

// ---------------- K6: compact candidates (bin >= B)
__global__ void k_compact(const u64* __restrict__ keys, u32* __restrict__ ctrl,
                          u64* __restrict__ candK, u32* __restrict__ candG) {
  int g = blockIdx.x * 256 + threadIdx.x;
  if (g >= NA) return;
  u32 binB = ctrl[0];
  u64 k = keys[g];
  if ((u32)(k >> 48) >= binB) {
    u32 idx = atomicAdd(&ctrl[2], 1u);
    candK[idx] = k;
    candG[idx] = g;
  }
}

// ---------------- K7: exact rank by counting; scatter top-4000 in sorted order
__global__ void k_rank(const u64* __restrict__ candK, const u32* __restrict__ candG,
                       const u32* __restrict__ ctrl, const double4* __restrict__ boxesd,
                       const float* __restrict__ smask, double4* __restrict__ tb,
                       float* __restrict__ ts) {
  __shared__ u64 kk[256];
  u32 m = ctrl[2];
  if (blockIdx.x * 256 >= m) return;        // prune empty blocks
  int i = blockIdx.x * 256 + threadIdx.x;
  u64 my = (i < (int)m) ? candK[i] : 0ULL;
  u32 rank = 0;
  for (u32 base = 0; base < m; base += 256) {
    u32 j = base + threadIdx.x;
    kk[threadIdx.x] = (j < m) ? candK[j] : 0ULL;
    __syncthreads();
    u32 lim = m - base; if (lim > 256) lim = 256;
    for (u32 tt = 0; tt < lim; tt++) rank += (kk[tt] > my) ? 1u : 0u;
    __syncthreads();
  }
  if (i < (int)m && rank < PRE_N) {
    u32 g = candG[i];
    tb[rank] = boxesd[g];
    ts[rank] = smask[g];
  }
}

// ---------------- K8: NMS suppression bitmask; LAST block's wave 0 runs the greedy
//                  serial scan + output write (replaces k_nms)
__global__ void k_mask(const double4* __restrict__ tb, const float* __restrict__ ts,
                       u64* __restrict__ mask, u32* __restrict__ ctrl,
                       float* __restrict__ out) {
  __shared__ double4 bx[64];
  __shared__ bool lastb;
  const int tid = threadIdx.x;
  int w = blockIdx.x;                         // 0..62
  int i = blockIdx.y * 256 + tid;
  if (tid < 64) bx[tid] = tb[w * 64 + tid];
  __syncthreads();
  if (i < PRE_N) {
    double4 b = tb[i];
    double ai = (b.z - b.x + 1.0) * (b.w - b.y + 1.0);
    u64 word = 0;
#pragma unroll 8
    for (int j = 0; j < 64; j++) {
      int jg = w * 64 + j;
      double4 cc = bx[j];
      double xx1 = fmax(b.x, cc.x), yy1 = fmax(b.y, cc.y);
      double xx2 = fmin(b.z, cc.z), yy2 = fmin(b.w, cc.w);
      double iw = xx2 - xx1 + 1.0, ih = yy2 - yy1 + 1.0;
      iw = iw > 0.0 ? iw : 0.0; ih = ih > 0.0 ? ih : 0.0;
      double inter = iw * ih;
      double aj = (cc.z - cc.x + 1.0) * (cc.w - cc.y + 1.0);
      bool sup = (jg > i) && (inter > 0.7 * (ai + aj - inter));
      word |= sup ? (1ULL << j) : 0ULL;
    }
    mask[(size_t)i * MASKW + w] = word;
  }
  // ---- last-block finisher: greedy scan (coalesced row loads + readlane resolve)
  __threadfence();
  if (tid == 0) lastb = (atomicAdd(&ctrl[9], 1u) == (u32)(MASKW * 16 - 1));
  __syncthreads();
  if (!lastb) return;
  __threadfence();
  if (tid >= 64) return;
  {
    int lane = tid;
    u64 keep = 0;                               // lane t owns keep word t (t<63)
    for (int w2 = 0; w2 < MASKW; w2++) {
      float s = ts[w2 * 64 + lane];
      u64 b = __ballot(s > -5.0e8f);
      if (lane == w2) keep = b;
    }
    const bool ldok = (lane < MASKW);
#pragma unroll 1
    for (int c = 0; c < MASKW; c++) {
      u64 v[64];
#pragma unroll
      for (int j = 0; j < 64; j++)
        v[j] = ldok ? mask[(size_t)(c * 64 + j) * MASKW + lane] : 0ULL;
      u64 cur = (u64)(u32)__builtin_amdgcn_readlane((int)(u32)keep, c)
              | ((u64)(u32)__builtin_amdgcn_readlane((int)(u32)(keep >> 32), c) << 32);
#pragma unroll
      for (int j = 0; j < 64; j++) {
        u64 Dj = (u64)(u32)__builtin_amdgcn_readlane((int)(u32)v[j], c)
               | ((u64)(u32)__builtin_amdgcn_readlane((int)(u32)(v[j] >> 32), c) << 32);
        u64 msk = (u64)0 - ((cur >> j) & 1ULL);
        cur &= ~(Dj & msk);
      }
      if (lane == c) keep = cur;
      u64 supp = 0;
#pragma unroll
      for (int j = 0; j < 64; j++) {
        u64 msk = (u64)0 - ((cur >> j) & 1ULL);
        supp |= v[j] & msk;
      }
      keep &= ~supp;
    }
    int pc = __popcll(keep);
    int pre = pc;
#pragma unroll
    for (int off = 1; off < 64; off <<= 1) {
      int v2 = __shfl_up(pre, off);
      if (lane >= off) pre += v2;
    }
    pre -= pc;   // exclusive prefix
#pragma unroll 1
    for (int j = 0; j < 64; j++) {
      if ((keep >> j) & 1ULL) {
        int r = pre + __popcll(keep & ((1ULL << j) - 1ULL));
        if (r < POST_N) {
          int i2 = lane * 64 + j;
          double4 b = tb[i2];
          out[r * 4 + 0] = (float)b.x;
          out[r * 4 + 1] = (float)b.y;
          out[r * 4 + 2] = (float)b.z;
          out[r * 4 + 3] = (float)b.w;
          out[8000 + r] = ts[i2];
        }
      }
    }
  }
}

// =====================================================================
extern "C" void kernel_launch(void* const* d_in, const int* in_sizes, int n_in,
                              void* d_out, int out_size, void* d_ws, size_t ws_size,
                              hipStream_t stream) {
  const float* feats  = (const float*)d_in[1];
  const float* w_conv = (const float*)d_in[2];
  const float* b_conv = (const float*)d_in[3];
  const float* w_cls  = (const float*)d_in[4];
  const float* b_cls  = (const float*)d_in[5];
  const float* w_reg  = (const float*)d_in[6];
  const float* b_reg  = (const float*)d_in[7];
  float* out = (float*)d_out;

  char* p = (char*)d_ws;
  auto carve = [&p](size_t bytes) -> void* {
    void* r = (void*)p;
    p += (bytes + 255) & ~(size_t)255;
    return r;
  };
  float*   fpad3   = (float*)carve(sizeof(float) * (P0 + 512));        // 51 MB
  float*   wt      = (float*)carve(sizeof(float) * 9216 * 512);        // 19 MB
  float*   wT      = (float*)carve(sizeof(float) * P2);
  float*   bT      = (float*)carve(sizeof(float) * 48);
  float*   hid     = (float*)carve(sizeof(float) * COUT * HIDP);       //  8.4 MB
  float*   hidp    = (float*)carve(sizeof(float) * KSLICES * COUT * HIDP); // 67 MB
  float*   scoresb = (float*)carve(sizeof(float) * 9 * NPOS);
  float*   deltab  = (float*)carve(sizeof(float) * 36 * NPOS);
  double4* boxesd  = (double4*)carve(sizeof(double4) * NA);
  u64*     keys    = (u64*)carve(sizeof(u64) * NA);
  float*   smask   = (float*)carve(sizeof(float) * NA);
  u32*     hist    = (u32*)carve(sizeof(u32) * 65536);
  u32*     ctrl    = (u32*)carve(256);
  u32*     cnt     = (u32*)carve(sizeof(u32) * 512);
  u64*     candK   = (u64*)carve(sizeof(u64) * NA);
  u32*     candG   = (u32*)carve(sizeof(u32) * NA);
  double4* tb      = (double4*)carve(sizeof(double4) * TBN);
  float*   ts      = (float*)carve(sizeof(float) * TBN);
  u64*     maskb   = (u64*)carve(sizeof(u64) * (size_t)TBN * MASKW);   //  2.0 MB
  (void)ws_size; (void)in_sizes; (void)n_in; (void)out_size;           // ~152 MB total

  k_prep<<<PREP_BLKS + WT_BLKS, 256, 0, stream>>>(feats, w_conv, w_cls, b_cls, w_reg, b_reg,
                                                  fpad3, wt, wT, bT, hist, ctrl, cnt, tb, ts);
  k_conv<<<dim3(32, 16, KSLICES), 256, 0, stream>>>(fpad3, wt, b_conv, hidp, hid, cnt);
  k_head<<<dim3(64, 4), 256, 0, stream>>>(hid, wT, bT, scoresb, deltab);
  k_prop<<<134, 256, 0, stream>>>(scoresb, deltab, boxesd, keys, smask, hist, ctrl, out);
  k_compact<<<134, 256, 0, stream>>>(keys, ctrl, candK, candG);
  k_rank<<<134, 256, 0, stream>>>(candK, candG, ctrl, boxesd, smask, tb, ts);
  k_mask<<<dim3(MASKW, 16), 256, 0, stream>>>(tb, ts, maskb, ctrl, out);
}

// Round 18
// 958.014 us; speedup vs baseline: 1.8198x; 1.8198x over previous
//
#include <hip/hip_runtime.h>
#include <stdint.h>
#include <math.h>

typedef unsigned long long u64;
typedef unsigned int u32;

#define CIN     1024
#define COUT    512
#define FH      50
#define FW      76
#define QP      80
#define HIDP    4096
#define FPITCH  4160            // 52*80
#define NPOS    3800
#define NA      34200
#define PRE_N   4000
#define POST_N  2000
#define MASKW   63
#define TBN     4032
#define KSLICES 8
#define CPS     128             // cins per slice; fold every 8 cins -> 72-ks fp32 segments (bit-identical)
#define QT      128             // q-tile (2 q per lane)
#define SPP     (CPS/2)         // cin-pair steps per slice = 64

#define P0 (3*CIN*FPITCH)       // fpad3 elements
#define P2 (512*48)             // wT elements
#define P3 65536                // init range
#define PREP_BLKS ((P0+P2+P3)/256)   // 50272
#define WT_BLKS   (144*8)            // 1152 transpose tiles

// ---------------- async global->LDS (16B granule: per-lane src, lds dest = base + lane*16)
__device__ __forceinline__ void async16(const float* g, float* l) {
  __builtin_amdgcn_global_load_lds(
      (__attribute__((address_space(1))) void*)(g),
      (__attribute__((address_space(3))) void*)(l), 16, 0, 0);
}

// ---------------- K0: fused prep — fpad3, conv-weight transpose, wT/bT, init
__global__ void k_prep(const float* __restrict__ feats, const float* __restrict__ w_conv,
                       const float* __restrict__ w_cls, const float* __restrict__ b_cls,
                       const float* __restrict__ w_reg, const float* __restrict__ b_reg,
                       float* __restrict__ fpad3, float* __restrict__ wt,
                       float* __restrict__ wT, float* __restrict__ bT,
                       u32* __restrict__ hist, u32* __restrict__ ctrl,
                       double4* __restrict__ tb, float* __restrict__ ts) {
  __shared__ float t[64][65];
  if (blockIdx.x >= PREP_BLKS) {
    // proven R1 transpose tile: w[oc][k] -> wt[k][oc]
    int bt_ = blockIdx.x - PREP_BLKS;
    int kx = bt_ % 144, oy = bt_ / 144;
    int k0 = kx * 64, oc0 = oy * 64;
    int tx = threadIdx.x & 63, tg = threadIdx.x >> 6;
#pragma unroll
    for (int rr = 0; rr < 16; rr++) {
      int row = tg * 16 + rr;
      t[row][tx] = w_conv[(size_t)(oc0 + row) * 9216 + k0 + tx];
    }
    __syncthreads();
#pragma unroll
    for (int rr = 0; rr < 16; rr++) {
      int kr = tg * 16 + rr;
      wt[(size_t)(k0 + kr) * 512 + oc0 + tx] = t[tx][kr];
    }
    return;
  }
  int idx = blockIdx.x * 256 + threadIdx.x;
  if (idx < P0) {
    int tc = idx / (CIN * FPITCH);
    int rem = idx - tc * (CIN * FPITCH);
    int cin = rem / FPITCH;
    int j = rem - cin * FPITCH + tc;
    float v = 0.f;
    if (j < FPITCH) {
      int r = j / QP, u = j - r * QP;
      if (r >= 1 && r <= FH && u >= 1 && u <= FW)
        v = feats[cin * (FH * FW) + (r - 1) * FW + (u - 1)];
    }
    fpad3[idx] = v;
    return;
  }
  idx -= P0;
  if (idx < P2) {
    int c = idx / 48, o = idx - c * 48;
    float v = 0.f;
    if (o < 9) v = w_cls[(size_t)(9 + o) * 512 + c];
    else if (o < 45) v = w_reg[(size_t)(o - 9) * 512 + c];
    wT[idx] = v;
    return;
  }
  idx -= P2;
  if (idx < P3) {
    hist[idx] = 0;
    if (idx < 8) ctrl[idx] = 0;
    if (idx < 48) bT[idx] = (idx < 9) ? b_cls[9 + idx] : (idx < 45 ? b_reg[idx - 9] : 0.f);
    if (idx >= PRE_N && idx < TBN) { tb[idx] = make_double4(0.0, 0.0, 0.0, 0.0); ts[idx] = -1.0e9f; }
  }
}

// ---------------- K2: conv3x3 split-K; cin-PAIR per step, weights via s_load, 6 waves/SIMD
__global__ __launch_bounds__(256, 6) void k_conv(const float* __restrict__ fpad3,
                                                 const float* __restrict__ wt,
                                                 float* __restrict__ hidp) {
  __shared__ __align__(16) float Bl[2][2][10][QT];   // 20.5 KiB: [buf][ci][row(9+dup)][q]
  const int tid = threadIdx.x;
  const int lane = tid & 63;
  const int wv = __builtin_amdgcn_readfirstlane(tid >> 6);
  const int q0 = blockIdx.x * QT;                    // 32 q-tiles of 128
  const int ws = (blockIdx.y << 2) + wv;             // oc-slice 0..63 (8 oc each)
  const int c0 = blockIdx.z * CPS;

  // wave wv stages rows 2wv (lanes 0-31), 2wv+1 (lanes 32-63); wave 0 also row 8 (dup 8,9)
  int rA = 2 * wv + (lane >> 5);
  int trA = rA / 3, tcA = rA - trA * 3;
  u32 voffA = (u32)tcA * (CIN * FPITCH) + (u32)trA * QP + q0 + (lane & 31) * 4;
  u32 voffB = 2u * (CIN * FPITCH) + 2u * QP + q0 + (lane & 31) * 4;   // row 8

  float acc32[8][2];
  double acc64[8][2];
#pragma unroll
  for (int i = 0; i < 8; i++) {
    acc32[i][0] = acc32[i][1] = 0.f;
    acc64[i][0] = acc64[i][1] = 0.0;
  }

#define STAGE(buf, sp)  do {                                                    \
    const float* _b0 = fpad3 + (size_t)(c0 + 2 * (sp)) * FPITCH;                \
    async16(_b0 + voffA, &Bl[buf][0][2 * wv][0]);                               \
    if (wv == 0) async16(_b0 + voffB, &Bl[buf][0][8][0]);                       \
    const float* _b1 = _b0 + FPITCH;                                            \
    async16(_b1 + voffA, &Bl[buf][1][2 * wv][0]);                               \
    if (wv == 0) async16(_b1 + voffB, &Bl[buf][1][8][0]);                       \
  } while (0)

  STAGE(0, 0);

#pragma unroll 1
  for (int sp = 0; sp < SPP; sp++) {
    __syncthreads();                                 // stage(sp) landed
    if (sp + 1 < SPP) STAGE((sp + 1) & 1, sp + 1);
    const int b0 = sp & 1;
#pragma unroll
    for (int ci = 0; ci < 2; ci++) {
      const int cin = c0 + 2 * sp + ci;
      const float* wp = wt + (((size_t)cin * 9) << 9) + (ws << 3);   // uniform -> s_load
#pragma unroll
      for (int ks = 0; ks < 9; ks++) {
        float2 b2 = *(const float2*)&Bl[b0][ci][ks][lane * 2];
        const float* w8 = wp + (ks << 9);
#pragma unroll
        for (int i = 0; i < 8; i++) {
          float w = w8[i];
          acc32[i][0] = fmaf(w, b2.x, acc32[i][0]);
          acc32[i][1] = fmaf(w, b2.y, acc32[i][1]);
        }
      }
    }
    if ((sp & 3) == 3) {                             // fold every 4 pairs = 8 cins (72 ks)
#pragma unroll
      for (int i = 0; i < 8; i++) {
        acc64[i][0] += (double)acc32[i][0]; acc32[i][0] = 0.f;
        acc64[i][1] += (double)acc32[i][1]; acc32[i][1] = 0.f;
      }
    }
  }
#undef STAGE

#pragma unroll
  for (int i = 0; i < 8; i++) {
    float2 o;
    o.x = (float)acc64[i][0];
    o.y = (float)acc64[i][1];
    *(float2*)&hidp[((size_t)(blockIdx.z * COUT + (ws << 3) + i) << 12) + q0 + lane * 2] = o;
  }
}

// ---------------- K2b: reduce 8 K-slice partials + bias + relu (fp64 left-fold)
__global__ void k_reduce(const float* __restrict__ hidp, const float* __restrict__ bconv,
                         float* __restrict__ hid) {
  int idx = blockIdx.x * 256 + threadIdx.x;          // 2,097,152 total
  int oc = idx >> 12;
  double s = 0.0;
#pragma unroll
  for (int z = 0; z < KSLICES; z++)
    s += (double)hidp[idx + ((size_t)z << 21)];
  s += (double)bconv[oc];
  hid[idx] = s > 0.0 ? (float)s : 0.f;
}

// ---------------- K3: 1x1 conv heads; grid (64,4), 3 outputs/thread, fp64 c-ascending
__global__ __launch_bounds__(256, 8) void k_head(const float* __restrict__ hid,
                                                 const float* __restrict__ wT,
                                                 const float* __restrict__ bT,
                                                 float* __restrict__ scoresb,
                                                 float* __restrict__ deltab) {
  int lane = threadIdx.x & 63;
  int wv = threadIdx.x >> 6;
  int q = blockIdx.x * 64 + lane;            // padded-q space
  int og = blockIdx.y * 12 + wv * 3;         // output group base (0..45)
  double acc0 = 0.0, acc1 = 0.0, acc2 = 0.0;
#pragma unroll 4
  for (int c = 0; c < 512; c++) {
    double hv = (double)hid[((size_t)c << 12) + q];
    const float* wr = wT + c * 48 + og;      // uniform per wave -> s_load
    acc0 += hv * (double)wr[0];
    acc1 += hv * (double)wr[1];
    acc2 += hv * (double)wr[2];
  }
  int y = q / QP, x = q - y * QP;
  if (x < FW && y < FH) {
    int pos = y * FW + x;
    double a[3] = {acc0, acc1, acc2};
#pragma unroll
    for (int j = 0; j < 3; j++) {
      int o = og + j;
      float r = (float)(a[j] + (double)bT[o]);
      if (o < 9)       scoresb[o * NPOS + pos] = r;
      else if (o < 45) deltab[(o - 9) * NPOS + pos] = r;
    }
  }
}

// ---------------- K4: proposals (fp64), keys; histogram stored TRANSPOSED for k_scan
__device__ __constant__ float AW[9] = {184.f, 368.f, 736.f, 128.f, 256.f, 512.f, 88.f, 176.f, 352.f};
__device__ __constant__ float AH[9] = {96.f, 192.f, 384.f, 128.f, 256.f, 512.f, 176.f, 352.f, 704.f};

__global__ void k_prop(const float* __restrict__ scoresb, const float* __restrict__ deltab,
                       double4* __restrict__ boxesd, u64* __restrict__ keys,
                       float* __restrict__ smask, u32* __restrict__ hist,
                       float* __restrict__ dout) {
  int g = blockIdx.x * 256 + threadIdx.x;
  if (g < 10000) dout[g] = 0.f;            // zero the harness-poisoned output
  if (g >= NA) return;
  int pos = g / 9, a = g - pos * 9;
  int y = pos / FW, x = pos - y * FW;
  double w = (double)AW[a], h = (double)AH[a];
  double cx = x * 16.0 + 8.0, cy = y * 16.0 + 8.0;
  double d0 = (double)deltab[(4 * a + 0) * NPOS + pos];
  double d1 = (double)deltab[(4 * a + 1) * NPOS + pos];
  double d2 = (double)deltab[(4 * a + 2) * NPOS + pos];
  double d3 = (double)deltab[(4 * a + 3) * NPOS + pos];
  double pcx = d0 * w + cx, pcy = d1 * h + cy;
  double pw = exp(d2) * w, ph = exp(d3) * h;
  double px1 = fmin(fmax(pcx - 0.5 * pw, 0.0), 1215.0);
  double py1 = fmin(fmax(pcy - 0.5 * ph, 0.0), 799.0);
  double px2 = fmin(fmax(pcx + 0.5 * pw, 0.0), 1215.0);
  double py2 = fmin(fmax(pcy + 0.5 * ph, 0.0), 799.0);
  bool valid = (px2 - px1 + 1.0 >= 16.0) && (py2 - py1 + 1.0 >= 16.0);
  float sc = scoresb[a * NPOS + pos];
  float ms = valid ? sc : -1.0e9f;
  boxesd[g] = make_double4(px1, py1, px2, py2);
  smask[g] = ms;
  u32 u = __float_as_uint(ms);
  u = (u >> 31) ? ~u : (u | 0x80000000u);            // monotone float->uint
  keys[g] = ((u64)u << 32) | (u32)(~(u32)g);         // score desc, index asc
  atomicAdd(&hist[(((u >> 16) & 0xFFu) << 8) | (u >> 24)], 1u);   // transposed bin
}

// ---------------- K5: cutoff bin for top-4000 (coalesced reads of transposed hist)
__global__ void k_scan(const u32* __restrict__ hist, u32* __restrict__ ctrl) {
  __shared__ u32 cs[256];
  __shared__ u32 sfx[256];
  int t = threadIdx.x;
  u32 s = 0;
  for (int i = 0; i < 256; i++) s += hist[(i << 8) | t];   // coalesced
  cs[t] = s;
  __syncthreads();
  if (t == 0) {
    u32 c = 0;
    for (int i = 255; i >= 0; i--) { sfx[i] = c; c += cs[i]; }
  }
  __syncthreads();
  u32 before = sfx[t];
  u32 c = 0;
  for (int blo = 255; blo >= 0; blo--) {
    u32 hv = hist[(blo << 8) | t];                   // coalesced
    if (before + c < PRE_N && before + c + hv >= PRE_N) {
      ctrl[0] = (u32)(t * 256 + blo);  // cutoff bin B (untransposed id)
      ctrl[1] = before + c;            // count strictly above B
    }
    c += hv;
  }
}

// ---------------- K6: compact candidates (bin >= B)
__global__ void k_compact(const u64* __restrict__ keys, u32* __restrict__ ctrl,
                          u64* __restrict__ candK, u32* __restrict__ candG) {
  int g = blockIdx.x * 256 + threadIdx.x;
  if (g >= NA) return;
  u32 binB = ctrl[0];
  u64 k = keys[g];
  if ((u32)(k >> 48) >= binB) {
    u32 idx = atomicAdd(&ctrl[2], 1u);
    candK[idx] = k;
    candG[idx] = g;
  }
}

// ---------------- K7: exact rank by counting; scatter top-4000 in sorted order
__global__ void k_rank(const u64* __restrict__ candK, const u32* __restrict__ candG,
                       const u32* __restrict__ ctrl, const double4* __restrict__ boxesd,
                       const float* __restrict__ smask, double4* __restrict__ tb,
                       float* __restrict__ ts) {
  __shared__ u64 kk[256];
  u32 m = ctrl[2];
  if (blockIdx.x * 256 >= m) return;        // prune empty blocks
  int i = blockIdx.x * 256 + threadIdx.x;
  u64 my = (i < (int)m) ? candK[i] : 0ULL;
  u32 rank = 0;
  for (u32 base = 0; base < m; base += 256) {
    u32 j = base + threadIdx.x;
    kk[threadIdx.x] = (j < m) ? candK[j] : 0ULL;
    __syncthreads();
    u32 lim = m - base; if (lim > 256) lim = 256;
    for (u32 tt = 0; tt < lim; tt++) rank += (kk[tt] > my) ? 1u : 0u;
    __syncthreads();
  }
  if (i < (int)m && rank < PRE_N) {
    u32 g = candG[i];
    tb[rank] = boxesd[g];
    ts[rank] = smask[g];
  }
}

// ---------------- K8: NMS suppression bitmask (fp64 IoU)
__global__ void k_mask(const double4* __restrict__ tb, u64* __restrict__ mask) {
  __shared__ double4 bx[64];
  int w = blockIdx.x;                         // 0..62
  int i = blockIdx.y * 256 + threadIdx.x;
  if (threadIdx.x < 64) bx[threadIdx.x] = tb[w * 64 + threadIdx.x];
  __syncthreads();
  if (i >= PRE_N) return;
  double4 b = tb[i];
  double ai = (b.z - b.x + 1.0) * (b.w - b.y + 1.0);
  u64 word = 0;
#pragma unroll 8
  for (int j = 0; j < 64; j++) {
    int jg = w * 64 + j;
    double4 cc = bx[j];
    double xx1 = fmax(b.x, cc.x), yy1 = fmax(b.y, cc.y);
    double xx2 = fmin(b.z, cc.z), yy2 = fmin(b.w, cc.w);
    double iw = xx2 - xx1 + 1.0, ih = yy2 - yy1 + 1.0;
    iw = iw > 0.0 ? iw : 0.0; ih = ih > 0.0 ? ih : 0.0;
    double inter = iw * ih;
    double aj = (cc.z - cc.x + 1.0) * (cc.w - cc.y + 1.0);
    bool sup = (jg > i) && (inter > 0.7 * (ai + aj - inter));
    word |= sup ? (1ULL << j) : 0ULL;
  }
  mask[(size_t)i * MASKW + w] = word;
}

// ---------------- K9: greedy scan — coalesced row loads + readlane serial resolve
__global__ __launch_bounds__(64, 1) void k_nms(const u64* __restrict__ mask,
                                               const float* __restrict__ ts,
                                               const double4* __restrict__ tb,
                                               float* __restrict__ out) {
  int lane = threadIdx.x;
  u64 keep = 0;                                 // lane t owns keep word t (t<63)
  for (int w = 0; w < MASKW; w++) {
    float s = ts[w * 64 + lane];
    u64 b = __ballot(s > -5.0e8f);
    if (lane == w) keep = b;
  }
  const bool ldok = (lane < MASKW);
#pragma unroll 1
  for (int c = 0; c < MASKW; c++) {
    u64 v[64];
#pragma unroll
    for (int j = 0; j < 64; j++)
      v[j] = ldok ? mask[(size_t)(c * 64 + j) * MASKW + lane] : 0ULL;
    u64 cur = (u64)(u32)__builtin_amdgcn_readlane((int)(u32)keep, c)
            | ((u64)(u32)__builtin_amdgcn_readlane((int)(u32)(keep >> 32), c) << 32);
#pragma unroll
    for (int j = 0; j < 64; j++) {
      u64 Dj = (u64)(u32)__builtin_amdgcn_readlane((int)(u32)v[j], c)
             | ((u64)(u32)__builtin_amdgcn_readlane((int)(u32)(v[j] >> 32), c) << 32);
      u64 msk = (u64)0 - ((cur >> j) & 1ULL);
      cur &= ~(Dj & msk);
    }
    if (lane == c) keep = cur;
    u64 supp = 0;
#pragma unroll
    for (int j = 0; j < 64; j++) {
      u64 msk = (u64)0 - ((cur >> j) & 1ULL);
      supp |= v[j] & msk;
    }
    keep &= ~supp;
  }
  int pc = __popcll(keep);
  int pre = pc;
#pragma unroll
  for (int off = 1; off < 64; off <<= 1) {
    int v2 = __shfl_up(pre, off);
    if (lane >= off) pre += v2;
  }
  pre -= pc;   // exclusive prefix
#pragma unroll 1
  for (int j = 0; j < 64; j++) {
    if ((keep >> j) & 1ULL) {
      int r = pre + __popcll(keep & ((1ULL << j) - 1ULL));
      if (r < POST_N) {
        int i = lane * 64 + j;
        double4 b = tb[i];
        out[r * 4 + 0] = (float)b.x;
        out[r * 4 + 1] = (float)b.y;
        out[r * 4 + 2] = (float)b.z;
        out[r * 4 + 3] = (float)b.w;
        out[8000 + r] = ts[i];
      }
    }
  }
}

// =====================================================================
extern "C" void kernel_launch(void* const* d_in, const int* in_sizes, int n_in,
                              void* d_out, int out_size, void* d_ws, size_t ws_size,
                              hipStream_t stream) {
  const float* feats  = (const float*)d_in[1];
  const float* w_conv = (const float*)d_in[2];
  const float* b_conv = (const float*)d_in[3];
  const float* w_cls  = (const float*)d_in[4];
  const float* b_cls  = (const float*)d_in[5];
  const float* w_reg  = (const float*)d_in[6];
  const float* b_reg  = (const float*)d_in[7];
  float* out = (float*)d_out;

  char* p = (char*)d_ws;
  auto carve = [&p](size_t bytes) -> void* {
    void* r = (void*)p;
    p += (bytes + 255) & ~(size_t)255;
    return r;
  };
  float*   fpad3   = (float*)carve(sizeof(float) * (P0 + 512));        // 51 MB
  float*   wt      = (float*)carve(sizeof(float) * 9216 * 512);        // 19 MB
  float*   wT      = (float*)carve(sizeof(float) * P2);
  float*   bT      = (float*)carve(sizeof(float) * 48);
  float*   hid     = (float*)carve(sizeof(float) * COUT * HIDP);       //  8.4 MB
  float*   hidp    = (float*)carve(sizeof(float) * KSLICES * COUT * HIDP); // 67 MB
  float*   scoresb = (float*)carve(sizeof(float) * 9 * NPOS);
  float*   deltab  = (float*)carve(sizeof(float) * 36 * NPOS);
  double4* boxesd  = (double4*)carve(sizeof(double4) * NA);
  u64*     keys    = (u64*)carve(sizeof(u64) * NA);
  float*   smask   = (float*)carve(sizeof(float) * NA);
  u32*     hist    = (u32*)carve(sizeof(u32) * 65536);
  u32*     ctrl    = (u32*)carve(256);
  u64*     candK   = (u64*)carve(sizeof(u64) * NA);
  u32*     candG   = (u32*)carve(sizeof(u32) * NA);
  double4* tb      = (double4*)carve(sizeof(double4) * TBN);
  float*   ts      = (float*)carve(sizeof(float) * TBN);
  u64*     maskb   = (u64*)carve(sizeof(u64) * (size_t)TBN * MASKW);   //  2.0 MB
  (void)ws_size; (void)in_sizes; (void)n_in; (void)out_size;           // ~152 MB total

  k_prep<<<PREP_BLKS + WT_BLKS, 256, 0, stream>>>(feats, w_conv, w_cls, b_cls, w_reg, b_reg,
                                                  fpad3, wt, wT, bT, hist, ctrl, tb, ts);
  k_conv<<<dim3(32, 16, KSLICES), 256, 0, stream>>>(fpad3, wt, hidp);
  k_reduce<<<8192, 256, 0, stream>>>(hidp, b_conv, hid);
  k_head<<<dim3(64, 4), 256, 0, stream>>>(hid, wT, bT, scoresb, deltab);
  k_prop<<<134, 256, 0, stream>>>(scoresb, deltab, boxesd, keys, smask, hist, out);
  k_scan<<<1, 256, 0, stream>>>(hist, ctrl);
  k_compact<<<134, 256, 0, stream>>>(keys, ctrl, candK, candG);
  k_rank<<<134, 256, 0, stream>>>(candK, candG, ctrl, boxesd, smask, tb, ts);
  k_mask<<<dim3(MASKW, 16), 256, 0, stream>>>(tb, maskb);
  k_nms<<<1, 64, 0, stream>>>(maskb, ts, tb, out);
}